// Round 6
// baseline (376.537 us; speedup 1.0000x reference)
//
#include <hip/hip_runtime.h>
#include <hip/hip_bf16.h>
#include <cmath>

#define DIM 512
#define HID 256
#define ROWS_PB 32       // rows per block
#define NCHUNK 16        // K chunks of 32
#define CB 16384         // chunk bytes: 32k * 256c * 2B

typedef __attribute__((ext_vector_type(8))) short short8;
typedef __attribute__((ext_vector_type(4))) float f32x4;

__device__ __forceinline__ unsigned short f2bf(float f) {
  union { float f; unsigned u; } v; v.f = f;
  unsigned u = v.u;
  return (unsigned short)((u + 0x7FFFu + ((u >> 16) & 1u)) >> 16);
}
__device__ __forceinline__ float bf2f(short h) {
  union { unsigned u; float f; } v;
  v.u = ((unsigned)(unsigned short)h) << 16;
  return v.f;
}

// Pre-swizzle W1 (fp32 [512,256] row-major) into bf16 MFMA fragment order:
// w1s[((k>>3)*HID + c)*8 + (k&7)]. K-chunk c (32 k's) is the contiguous
// 16 KB at byte offset c*16384 — a linear global_load_lds copy.
__global__ void w1_swz_kernel(const float* __restrict__ W1,
                              unsigned short* __restrict__ w1s) {
  int tid = blockIdx.x * blockDim.x + threadIdx.x;
  if (tid >= DIM * HID) return;
  int k = tid / HID;
  int c = tid - k * HID;
  w1s[(((k >> 3) * HID) + c) * 8 + (k & 7)] = f2bf(W1[tid]);
}

__device__ __forceinline__ short8 cvt8(const f32x4 p0, const f32x4 p1) {
  short8 r;
  r[0] = (short)f2bf(p0[0]); r[1] = (short)f2bf(p0[1]);
  r[2] = (short)f2bf(p0[2]); r[3] = (short)f2bf(p0[3]);
  r[4] = (short)f2bf(p1[0]); r[5] = (short)f2bf(p1[1]);
  r[6] = (short)f2bf(p1[2]); r[7] = (short)f2bf(p1[3]);
  return r;
}

__device__ __forceinline__ void wcombine(float wa, const short8 a, float wb,
                                         const short8 b, f32x4& o0, f32x4& o1) {
#pragma unroll
  for (int i = 0; i < 4; ++i) {
    o0[i] = wa * bf2f(a[i]) + wb * bf2f(b[i]);
    o1[i] = wa * bf2f(a[i + 4]) + wb * bf2f(b[i + 4]);
  }
}

// 4 waves/block, 32 rows. Wave w: src s=w&1 (z1/z2), row-tile=w>>1.
// Phase 1: one deep burst loads the wave's whole A-tile (32 KB fp32) into
//          64 VGPRs of bf16 fragments — the ONLY HBM reads of the kernel.
// Phase 2: K-loop over 16 B-chunks (L2-resident w1s), triple-buffered LDS
//          via global_load_lds, one s_barrier per chunk, no HBM.
// Phase 3: logits; wave pairs exchange bf16 z-halves through LDS; write out.
__global__ __launch_bounds__(256, 3) void fa_main_kernel(
    const float* __restrict__ z1, const float* __restrict__ z2,
    const unsigned short* __restrict__ w1s,
    const float* __restrict__ b1, const float* __restrict__ W2,
    const float* __restrict__ b2, float* __restrict__ out, int n) {
  __shared__ unsigned short Bs[3][CB / 2];  // 48 KB triple buffer
  __shared__ float xs[2][ROWS_PB];

  const int t = threadIdx.x;
  const int w = t >> 6;
  const int l = t & 63;
  const int l15 = l & 15, l16 = l >> 4;
  const int s = w & 1;
  const int tile = w >> 1;
  const int row0 = blockIdx.x * ROWS_PB;
  const int myrow = row0 + tile * 16 + l15;
  const bool rok = myrow < n;
  const float* zz = s ? z2 : z1;
  const float* ap = zz + (size_t)myrow * DIM + (l16 << 3);
  const f32x4 zf4 = (f32x4){0.f, 0.f, 0.f, 0.f};

  auto STAGE = [&](int cc, int buf) {
    const char* gsrc = (const char*)w1s + cc * CB + l * 16;
    char* ldst = (char*)&Bs[buf][0];
#pragma unroll
    for (int r = 0; r < 4; ++r) {
      const int rr = w + r * 4;
      __builtin_amdgcn_global_load_lds(
          (const __attribute__((address_space(1))) void*)(gsrc + rr * 1024),
          (__attribute__((address_space(3))) void*)(ldst + rr * 1024), 16, 0,
          0);
    }
  };

  STAGE(0, 0);
  __builtin_amdgcn_sched_barrier(0);

  // Phase 1: burst-load A (16 fragments = 16 rows x 512 cols for this wave).
  short8 areg[NCHUNK];
#pragma unroll
  for (int c = 0; c < NCHUNK; ++c) {
    const float* p = ap + (c << 5);
    const f32x4 p0 = rok ? *(const f32x4*)(p) : zf4;
    const f32x4 p1 = rok ? *(const f32x4*)(p + 4) : zf4;
    areg[c] = cvt8(p0, p1);
  }

  f32x4 acc[16];
#pragma unroll
  for (int f = 0; f < 16; ++f) acc[f] = zf4;

  asm volatile("s_waitcnt vmcnt(0)" ::: "memory");
  __builtin_amdgcn_s_barrier();

  // Phase 2: K-loop, B-only traffic (L2), one barrier per chunk.
#pragma unroll
  for (int c = 0; c < NCHUNK; ++c) {
    if (c + 1 < NCHUNK) STAGE(c + 1, (c + 1) % 3);
    __builtin_amdgcn_sched_barrier(0);
    const short8 af = areg[c];
    const short8* bp = (const short8*)&Bs[c % 3][0] + (l16 << 8) + l15;
#pragma unroll
    for (int f = 0; f < 16; ++f) {
      const short8 bf = bp[f << 4];
      acc[f] = __builtin_amdgcn_mfma_f32_16x16x32_bf16(af, bf, acc[f], 0, 0, 0);
    }
    if (c + 1 < NCHUNK) asm volatile("s_waitcnt vmcnt(0)" ::: "memory");
    __builtin_amdgcn_s_barrier();  // all waves' B[c+1] landed; buf rotation ok
  }

  // Phase 3a: per-row logits. C/D: hidden col = l15+16f, row = l16*4+r.
  float part[4] = {0.f, 0.f, 0.f, 0.f};
#pragma unroll
  for (int f = 0; f < 16; ++f) {
    const int cc = (f << 4) + l15;
    const float w2v = W2[cc];
    const float b1v = b1[cc];
#pragma unroll
    for (int r = 0; r < 4; ++r) {
      const float h = acc[f][r] + b1v;
      part[r] += (h > 0.f) ? h * w2v : 0.f;
    }
  }
#pragma unroll
  for (int r = 0; r < 4; ++r) {
#pragma unroll
    for (int m = 1; m < 16; m <<= 1) part[r] += __shfl_xor(part[r], m, 16);
  }

  // Phase 3b: exchange. Wave w writes the 8 chunks its partner (w^1) needs:
  // chunks (1-s)*8..+8. Layout: byte = w*8192 + j*1024 + l*16 (lane-linear).
  // Safe to overwrite Bs: final K-loop barrier guarantees all ds_reads done.
  {
    char* ebase = (char*)&Bs[0][0] + w * 8192 + l * 16;
    if (s == 0) {
#pragma unroll
      for (int j = 0; j < 8; ++j) *(short8*)(ebase + j * 1024) = areg[8 + j];
    } else {
#pragma unroll
      for (int j = 0; j < 8; ++j) *(short8*)(ebase + j * 1024) = areg[j];
    }
  }
  if (l15 == 0) {
#pragma unroll
    for (int r = 0; r < 4; ++r) xs[s][tile * 16 + (l16 << 2) + r] = part[r];
  }
  __syncthreads();

  // Phase 3c: out[row, s*256 + j*32 + l16*8 ..] = sx*z1 + sy*z2 (b2 cancels).
  const float x = xs[0][tile * 16 + l15];
  const float y = xs[1][tile * 16 + l15];
  const float d = y - x;
  const float sx = 1.f / (1.f + __expf(d));
  const float sy = 1.f - sx;
  const float wOwn = s ? sy : sx;
  const float wOth = s ? sx : sy;
  const char* pbase = (const char*)&Bs[0][0] + (w ^ 1) * 8192 + l * 16;
  float* orow = out + (size_t)myrow * DIM + (s << 8) + (l16 << 3);
  if (rok) {
    if (s == 0) {
#pragma unroll
      for (int j = 0; j < 8; ++j) {
        const short8 ov = *(const short8*)(pbase + j * 1024);
        f32x4 o0, o1;
        wcombine(wOwn, areg[j], wOth, ov, o0, o1);
        *(f32x4*)(orow + j * 32) = o0;
        *(f32x4*)(orow + j * 32 + 4) = o1;
      }
    } else {
#pragma unroll
      for (int j = 0; j < 8; ++j) {
        const short8 ov = *(const short8*)(pbase + j * 1024);
        f32x4 o0, o1;
        wcombine(wOwn, areg[8 + j], wOth, ov, o0, o1);
        *(f32x4*)(orow + j * 32) = o0;
        *(f32x4*)(orow + j * 32 + 4) = o1;
      }
    }
  }
}

extern "C" void kernel_launch(void* const* d_in, const int* in_sizes, int n_in,
                              void* d_out, int out_size, void* d_ws,
                              size_t ws_size, hipStream_t stream) {
  const float* z1 = (const float*)d_in[0];
  const float* z2 = (const float*)d_in[1];
  const float* W1 = (const float*)d_in[2];
  const float* b1 = (const float*)d_in[3];
  const float* W2 = (const float*)d_in[4];
  const float* b2 = (const float*)d_in[5];
  float* out = (float*)d_out;
  const int n = in_sizes[0] / DIM;
  unsigned short* w1s = (unsigned short*)d_ws;  // 512*256*2 = 256 KB

  hipLaunchKernelGGL(w1_swz_kernel, dim3((DIM * HID + 255) / 256), dim3(256),
                     0, stream, W1, w1s);
  const int nwg = (n + ROWS_PB - 1) / ROWS_PB;
  hipLaunchKernelGGL(fa_main_kernel, dim3(nwg), dim3(256), 0, stream, z1, z2,
                     w1s, b1, W2, b2, out, n);
}

// Round 7
// 225.957 us; speedup vs baseline: 1.6664x; 1.6664x over previous
//
#include <hip/hip_runtime.h>
#include <hip/hip_bf16.h>
#include <cmath>

#define DIM 512
#define HID 256
#define ROWS_PB 16       // rows per block (100000 = 6250 * 16, no tail)
#define NCHUNK 16        // K chunks of 32
#define CB 16384         // B chunk bytes: 32k * 256c * 2B

typedef __attribute__((ext_vector_type(8))) short short8;
typedef __attribute__((ext_vector_type(4))) float f32x4;

__device__ __forceinline__ unsigned short f2bf(float f) {
  union { float f; unsigned u; } v; v.f = f;
  unsigned u = v.u;
  return (unsigned short)((u + 0x7FFFu + ((u >> 16) & 1u)) >> 16);
}
__device__ __forceinline__ float bf2f(short h) {
  union { unsigned u; float f; } v;
  v.u = ((unsigned)(unsigned short)h) << 16;
  return v.f;
}

// Pre-swizzle W1 (fp32 [512,256] row-major) into bf16 MFMA fragment order:
// w1s[((k>>3)*HID + c)*8 + (k&7)]. K-chunk c (32 k's) is the contiguous
// 16 KB at byte offset c*16384 — a linear global_load_lds copy.
__global__ void w1_swz_kernel(const float* __restrict__ W1,
                              unsigned short* __restrict__ w1s) {
  int tid = blockIdx.x * blockDim.x + threadIdx.x;
  if (tid >= DIM * HID) return;
  int k = tid / HID;
  int c = tid - k * HID;
  w1s[(((k >> 3) * HID) + c) * 8 + (k & 7)] = f2bf(W1[tid]);
}

__device__ __forceinline__ short8 cvt8(const f32x4 p0, const f32x4 p1) {
  short8 r;
  r[0] = (short)f2bf(p0[0]); r[1] = (short)f2bf(p0[1]);
  r[2] = (short)f2bf(p0[2]); r[3] = (short)f2bf(p0[3]);
  r[4] = (short)f2bf(p1[0]); r[5] = (short)f2bf(p1[1]);
  r[6] = (short)f2bf(p1[2]); r[7] = (short)f2bf(p1[3]);
  return r;
}

__device__ __forceinline__ void wcombine(float wa, const short8 a, float wb,
                                         const short8 b, f32x4& o0, f32x4& o1) {
#pragma unroll
  for (int i = 0; i < 4; ++i) {
    o0[i] = wa * bf2f(a[i]) + wb * bf2f(b[i]);
    o1[i] = wa * bf2f(a[i + 4]) + wb * bf2f(b[i + 4]);
  }
}

// 4 waves / 16 rows. Wave w: src s=w&1 (z1/z2), hid-half h=w>>1.
// Phase 1: deep burst — each wave loads 16KB of its source's rows (16
//          independent dwordx4/lane), cvt to bf16, store to LDS Az (32 KB
//          total: BOTH sources for the block's 16 rows). Only HBM reads.
// Phase 2: A-fragments hoisted to 64 VGPRs; K-loop over 16 B-chunks
//          (L2-resident w1s, double-buffered LDS). Zero HBM.
// Phase 3: HID-split partial logits combined via LDS; epilogue computes
//          out = sx*z1 + sy*z2 entirely from Az. Only HBM writes.
__global__ __launch_bounds__(256, 2) void fa_main_kernel(
    const float* __restrict__ z1, const float* __restrict__ z2,
    const unsigned short* __restrict__ w1s,
    const float* __restrict__ b1, const float* __restrict__ W2,
    const float* __restrict__ b2, float* __restrict__ out, int n) {
  __shared__ short8 Az[2][NCHUNK][64];       // 32 KB: [src][chunk][lane]
  __shared__ unsigned short Bs[2][CB / 2];   // 32 KB double buffer
  __shared__ float xs2[2][2][ROWS_PB];       // partial logits [src][half][row]

  const int t = threadIdx.x;
  const int w = t >> 6;
  const int l = t & 63;
  const int l15 = l & 15, l16 = l >> 4;
  const int s = w & 1;   // source this wave stages/scores
  const int h = w >> 1;  // hid-half this wave computes
  const int row0 = blockIdx.x * ROWS_PB;
  const int myrow = row0 + l15;
  const bool rok = myrow < n;
  const float* zz = s ? z2 : z1;
  const float* ap = zz + (size_t)myrow * DIM + (l16 << 3);
  const f32x4 zf4 = (f32x4){0.f, 0.f, 0.f, 0.f};

  auto STAGE = [&](int cc, int buf) {
    const char* gsrc = (const char*)w1s + cc * CB + l * 16;
    char* ldst = (char*)&Bs[buf][0];
#pragma unroll
    for (int r = 0; r < 4; ++r) {
      const int rr = w + r * 4;
      __builtin_amdgcn_global_load_lds(
          (const __attribute__((address_space(1))) void*)(gsrc + rr * 1024),
          (__attribute__((address_space(3))) void*)(ldst + rr * 1024), 16, 0,
          0);
    }
  };

  STAGE(0, 0);
  __builtin_amdgcn_sched_barrier(0);

  // Phase 1: wave w bursts its source's chunks [h*8, h*8+8): 16 independent
  // 16B/lane loads all in flight, then cvt+ds_write as they land.
  {
    f32x4 pp[8][2];
#pragma unroll
    for (int j = 0; j < 8; ++j) {
      const float* p = ap + ((h * 8 + j) << 5);
      pp[j][0] = rok ? *(const f32x4*)(p) : zf4;
      pp[j][1] = rok ? *(const f32x4*)(p + 4) : zf4;
    }
#pragma unroll
    for (int j = 0; j < 8; ++j)
      Az[s][h * 8 + j][l] = cvt8(pp[j][0], pp[j][1]);
  }
  __syncthreads();  // Az complete + B0 landed

  // Hoist all A-fragments into registers (Az is immutable from here).
  short8 af[NCHUNK];
#pragma unroll
  for (int c = 0; c < NCHUNK; ++c) af[c] = Az[s][c][l];

  f32x4 acc[8];
#pragma unroll
  for (int f = 0; f < 8; ++f) acc[f] = zf4;

  // Phase 2: K-loop, B-only (L2) traffic, one barrier per chunk.
#pragma unroll
  for (int c = 0; c < NCHUNK; ++c) {
    if (c + 1 < NCHUNK) STAGE(c + 1, (c + 1) & 1);
    __builtin_amdgcn_sched_barrier(0);
    const short8* bp =
        (const short8*)&Bs[c & 1][0] + (l16 << 8) + (h << 7) + l15;
#pragma unroll
    for (int f = 0; f < 8; ++f) {
      const short8 bf = bp[f << 4];
      acc[f] =
          __builtin_amdgcn_mfma_f32_16x16x32_bf16(af[c], bf, acc[f], 0, 0, 0);
    }
    __syncthreads();  // drains B[c+1] stage; rotate buffers
  }

  // Phase 3a: partial logit over this wave's hid-half.
  // C/D: hidden col = h*128 + f*16 + l15, row = l16*4 + r.
  float part[4] = {0.f, 0.f, 0.f, 0.f};
#pragma unroll
  for (int f = 0; f < 8; ++f) {
    const int cc = (h << 7) + (f << 4) + l15;
    const float w2v = W2[cc];
    const float b1v = b1[cc];
#pragma unroll
    for (int r = 0; r < 4; ++r) {
      const float hh = acc[f][r] + b1v;
      part[r] += (hh > 0.f) ? hh * w2v : 0.f;
    }
  }
#pragma unroll
  for (int r = 0; r < 4; ++r) {
#pragma unroll
    for (int m = 1; m < 16; m <<= 1) part[r] += __shfl_xor(part[r], m, 16);
  }
  if (l15 == 0) {
#pragma unroll
    for (int r = 0; r < 4; ++r) xs2[s][h][(l16 << 2) + r] = part[r];
  }
  __syncthreads();

  // Phase 3b: scores + output, entirely from Az (no HBM reads).
  const float x = xs2[0][0][l15] + xs2[0][1][l15];
  const float y = xs2[1][0][l15] + xs2[1][1][l15];
  const float d = y - x;  // b2 cancels
  const float sx = 1.f / (1.f + __expf(d));
  const float sy = 1.f - sx;
  float* orow = out + (size_t)myrow * DIM + (l16 << 3);
  if (rok) {
#pragma unroll
    for (int j = 0; j < 4; ++j) {
      const int c = (w << 2) + j;  // wave w covers chunks w*4..w*4+4
      const short8 a0 = Az[0][c][l];
      const short8 a1 = Az[1][c][l];
      f32x4 o0, o1;
      wcombine(sx, a0, sy, a1, o0, o1);
      *(f32x4*)(orow + (c << 5)) = o0;
      *(f32x4*)(orow + (c << 5) + 4) = o1;
    }
  }
}

extern "C" void kernel_launch(void* const* d_in, const int* in_sizes, int n_in,
                              void* d_out, int out_size, void* d_ws,
                              size_t ws_size, hipStream_t stream) {
  const float* z1 = (const float*)d_in[0];
  const float* z2 = (const float*)d_in[1];
  const float* W1 = (const float*)d_in[2];
  const float* b1 = (const float*)d_in[3];
  const float* W2 = (const float*)d_in[4];
  const float* b2 = (const float*)d_in[5];
  float* out = (float*)d_out;
  const int n = in_sizes[0] / DIM;
  unsigned short* w1s = (unsigned short*)d_ws;  // 512*256*2 = 256 KB

  hipLaunchKernelGGL(w1_swz_kernel, dim3((DIM * HID + 255) / 256), dim3(256),
                     0, stream, W1, w1s);
  const int nwg = (n + ROWS_PB - 1) / ROWS_PB;
  hipLaunchKernelGGL(fa_main_kernel, dim3(nwg), dim3(256), 0, stream, z1, z2,
                     w1s, b1, W2, b2, out, n);
}

// Round 9
// 215.625 us; speedup vs baseline: 1.7463x; 1.0479x over previous
//
#include <hip/hip_runtime.h>
#include <hip/hip_bf16.h>
#include <cmath>

#define DIM 512
#define HID 256
#define ROWS_PB 16       // rows per block (100000 = 6250 * 16, no tail)
#define NCHUNK 16        // K chunks of 32

typedef __attribute__((ext_vector_type(8))) short short8;
typedef __attribute__((ext_vector_type(4))) float f32x4;

__device__ __forceinline__ unsigned short f2bf(float f) {
  union { float f; unsigned u; } v; v.f = f;
  unsigned u = v.u;
  return (unsigned short)((u + 0x7FFFu + ((u >> 16) & 1u)) >> 16);
}
__device__ __forceinline__ float bf2f(short h) {
  union { unsigned u; float f; } v;
  v.u = ((unsigned)(unsigned short)h) << 16;
  return v.f;
}

// Pre-swizzle W1 (fp32 [512,256] row-major) into bf16 MFMA fragment order:
// w1s[((k>>3)*HID + c)*8 + (k&7)]. Lane's B-fragment for k-group kg, col c
// is the contiguous 16 B at short8-index kg*HID + c.
__global__ void w1_swz_kernel(const float* __restrict__ W1,
                              unsigned short* __restrict__ w1s) {
  int tid = blockIdx.x * blockDim.x + threadIdx.x;
  if (tid >= DIM * HID) return;
  int k = tid / HID;
  int c = tid - k * HID;
  w1s[(((k >> 3) * HID) + c) * 8 + (k & 7)] = f2bf(W1[tid]);
}

__device__ __forceinline__ short8 cvt8(const f32x4 p0, const f32x4 p1) {
  short8 r;
  r[0] = (short)f2bf(p0[0]); r[1] = (short)f2bf(p0[1]);
  r[2] = (short)f2bf(p0[2]); r[3] = (short)f2bf(p0[3]);
  r[4] = (short)f2bf(p1[0]); r[5] = (short)f2bf(p1[1]);
  r[6] = (short)f2bf(p1[2]); r[7] = (short)f2bf(p1[3]);
  return r;
}

__device__ __forceinline__ void wcombine(float wa, const short8 a, float wb,
                                         const short8 b, f32x4& o0, f32x4& o1) {
#pragma unroll
  for (int i = 0; i < 4; ++i) {
    o0[i] = wa * bf2f(a[i]) + wb * bf2f(b[i]);
    o1[i] = wa * bf2f(a[i + 4]) + wb * bf2f(b[i + 4]);
  }
}

// 4 waves / 16 rows. Wave w: src s=w&1 (z1/z2), hid-half h=w>>1.
// Phase 1: deep HBM burst -> Az bf16 fragments in LDS (z read ONCE); one
//          __syncthreads; hoist all 16 A-fragments to VGPRs.
// Phase 2: ZERO barriers. B-fragments read directly from L2-resident w1s
//          into registers, double-buffered (b0/b1, static indexing). Each
//          wave is a fully independent load/MFMA stream.
// Phase 3: HID-split logits combined via LDS; out computed from Az only.
__global__ __launch_bounds__(256, 2) void fa_main_kernel(
    const float* __restrict__ z1, const float* __restrict__ z2,
    const unsigned short* __restrict__ w1s,
    const float* __restrict__ bias1, const float* __restrict__ W2,
    const float* __restrict__ bias2, float* __restrict__ out, int n) {
  __shared__ short8 Az[2 * NCHUNK * 64];  // 32 KB: [src][chunk][lane]
  __shared__ float xs2[2][2][ROWS_PB];    // partial logits [src][half][row]

  const int t = threadIdx.x;
  const int w = t >> 6;
  const int l = t & 63;
  const int l15 = l & 15, l16 = l >> 4;
  const int s = w & 1;   // source this wave stages/scores
  const int h = w >> 1;  // hid-half this wave computes
  const int row0 = blockIdx.x * ROWS_PB;
  const int myrow = row0 + l15;
  const bool rok = myrow < n;
  const float* zz = s ? z2 : z1;
  const float* ap = zz + (size_t)myrow * DIM + (l16 << 3);
  const f32x4 zf4 = (f32x4){0.f, 0.f, 0.f, 0.f};

  // Phase 1: A burst — 16 independent dwordx4/lane from HBM, cvt, ds_write.
  {
    f32x4 pp[8][2];
#pragma unroll
    for (int j = 0; j < 8; ++j) {
      const float* p = ap + ((h * 8 + j) << 5);
      pp[j][0] = rok ? *(const f32x4*)(p) : zf4;
      pp[j][1] = rok ? *(const f32x4*)(p + 4) : zf4;
    }
#pragma unroll
    for (int j = 0; j < 8; ++j)
      Az[(s * NCHUNK + h * 8 + j) * 64 + l] = cvt8(pp[j][0], pp[j][1]);
  }
  __syncthreads();  // Az complete — the only barrier before the epilogue one

  // Hoist all A-fragments (Az stays immutable for the epilogue).
  short8 af[NCHUNK];
#pragma unroll
  for (int c = 0; c < NCHUNK; ++c) af[c] = Az[(s * NCHUNK + c) * 64 + l];

  f32x4 acc[8];
#pragma unroll
  for (int f = 0; f < 8; ++f) acc[f] = zf4;

  // Phase 2: barrier-free K-loop; B direct from L2, 1-chunk lookahead.
  // Fragment (c,f): short8-index (c*4 + l16)*256 + h*128 + f*16 + l15.
  const short8* gB = (const short8*)w1s;
  const int bbase = (l16 << 8) + (h << 7) + l15;
  short8 b0[8], b1[8];
#pragma unroll
  for (int f = 0; f < 8; ++f) b0[f] = gB[bbase + (f << 4)];
#pragma unroll
  for (int cc = 0; cc < NCHUNK / 2; ++cc) {
    const int c0 = 2 * cc, c1 = 2 * cc + 1;
#pragma unroll
    for (int f = 0; f < 8; ++f) b1[f] = gB[(c1 << 10) + bbase + (f << 4)];
#pragma unroll
    for (int f = 0; f < 8; ++f)
      acc[f] = __builtin_amdgcn_mfma_f32_16x16x32_bf16(af[c0], b0[f], acc[f],
                                                       0, 0, 0);
    if (c1 + 1 < NCHUNK) {
#pragma unroll
      for (int f = 0; f < 8; ++f)
        b0[f] = gB[((c1 + 1) << 10) + bbase + (f << 4)];
    }
#pragma unroll
    for (int f = 0; f < 8; ++f)
      acc[f] = __builtin_amdgcn_mfma_f32_16x16x32_bf16(af[c1], b1[f], acc[f],
                                                       0, 0, 0);
  }

  // Phase 3a: partial logit over this wave's hid-half.
  // C/D: hidden col = h*128 + f*16 + l15, row = l16*4 + r.
  float part[4] = {0.f, 0.f, 0.f, 0.f};
#pragma unroll
  for (int f = 0; f < 8; ++f) {
    const int cc = (h << 7) + (f << 4) + l15;
    const float w2v = W2[cc];
    const float b1v = bias1[cc];
#pragma unroll
    for (int r = 0; r < 4; ++r) {
      const float hh = acc[f][r] + b1v;
      part[r] += (hh > 0.f) ? hh * w2v : 0.f;
    }
  }
#pragma unroll
  for (int r = 0; r < 4; ++r) {
#pragma unroll
    for (int m = 1; m < 16; m <<= 1) part[r] += __shfl_xor(part[r], m, 16);
  }
  if (l15 == 0) {
#pragma unroll
    for (int r = 0; r < 4; ++r) xs2[s][h][(l16 << 2) + r] = part[r];
  }
  __syncthreads();

  // Phase 3b: scores + output, entirely from Az (no HBM reads).
  const float x = xs2[0][0][l15] + xs2[0][1][l15];
  const float y = xs2[1][0][l15] + xs2[1][1][l15];
  const float d = y - x;  // b2 cancels in the pair difference
  const float sx = 1.f / (1.f + __expf(d));
  const float sy = 1.f - sx;
  float* orow = out + (size_t)myrow * DIM + (l16 << 3);
  if (rok) {
#pragma unroll
    for (int j = 0; j < 4; ++j) {
      const int c = (w << 2) + j;  // wave w covers chunks w*4..w*4+4
      const short8 a0 = Az[(0 * NCHUNK + c) * 64 + l];
      const short8 a1 = Az[(1 * NCHUNK + c) * 64 + l];
      f32x4 o0, o1;
      wcombine(sx, a0, sy, a1, o0, o1);
      *(f32x4*)(orow + (c << 5)) = o0;
      *(f32x4*)(orow + (c << 5) + 4) = o1;
    }
  }
}

extern "C" void kernel_launch(void* const* d_in, const int* in_sizes, int n_in,
                              void* d_out, int out_size, void* d_ws,
                              size_t ws_size, hipStream_t stream) {
  const float* z1 = (const float*)d_in[0];
  const float* z2 = (const float*)d_in[1];
  const float* W1 = (const float*)d_in[2];
  const float* b1 = (const float*)d_in[3];
  const float* W2 = (const float*)d_in[4];
  const float* b2 = (const float*)d_in[5];
  float* out = (float*)d_out;
  const int n = in_sizes[0] / DIM;
  unsigned short* w1s = (unsigned short*)d_ws;  // 512*256*2 = 256 KB

  hipLaunchKernelGGL(w1_swz_kernel, dim3((DIM * HID + 255) / 256), dim3(256),
                     0, stream, W1, w1s);
  const int nwg = (n + ROWS_PB - 1) / ROWS_PB;
  hipLaunchKernelGGL(fa_main_kernel, dim3(nwg), dim3(256), 0, stream, z1, z2,
                     w1s, b1, W2, b2, out, n);
}